// Round 5
// baseline (5451.991 us; speedup 1.0000x reference)
//
#include <hip/hip_runtime.h>
#include <stdint.h>

// ---------------------------------------------------------------------------
// 2-layer LSTM, B=64, T=512, E=512, H=1024, then [64,1024]@V.T+bV -> [64,10].
//
// Round 5: replace the per-tick centralized grid barrier (arrive->gather->
// release, 4-5 IC round trips on the serial spine) with DATAFLOW FLAGS:
//  - each WG keeps a monotone tick counter (sc1 store, 16B padded);
//  - consumers poll only the flag set they depend on (wave0: L0 flags,
//    wave4: L1 flags; L0 WGs never poll L1 at all), then one __syncthreads;
//  - spine per tick = flag store -> poll observe -> fill+MFMA -> flag store.
//  - R4's 128-deep write-once ring + revolution fences kept: full 256-flag
//    rendezvous + agent acquire fence at ticks 128/256/384/512. Rendezvous r
//    guarantees all rev r-1 reads (write-tick+1/+2) precede any rev-r
//    overwrite; exactly one L2-inv between any cross-revolution read pair.
// ---------------------------------------------------------------------------

typedef __attribute__((ext_vector_type(8))) short bf16x8;   // 8 bf16 in 4 VGPRs
typedef __attribute__((ext_vector_type(4))) float f32x4;

__device__ __forceinline__ unsigned short f2bf(float x) {
    unsigned u = __float_as_uint(x);
    u = (u + 0x7FFFu + ((u >> 16) & 1u)) >> 16;   // RNE
    return (unsigned short)u;
}

__device__ __forceinline__ f32x4 mfma16(bf16x8 a, bf16x8 b, f32x4 c) {
    return __builtin_amdgcn_mfma_f32_16x16x32_bf16(a, b, c, 0, 0, 0);
}

// agent-scope (IC-direct) 16B load — fallback path only
__device__ __forceinline__ bf16x8 ldh(const unsigned short* p) {
    union { unsigned long long q[2]; bf16x8 v; } u;
    unsigned long long* a = (unsigned long long*)p;
    u.q[0] = __hip_atomic_load(a + 0, __ATOMIC_RELAXED, __HIP_MEMORY_SCOPE_AGENT);
    u.q[1] = __hip_atomic_load(a + 1, __ATOMIC_RELAXED, __HIP_MEMORY_SCOPE_AGENT);
    return u.v;
}

__device__ __forceinline__ void spin_ge(const unsigned int* f, unsigned target) {
    while (__hip_atomic_load(f, __ATOMIC_RELAXED, __HIP_MEMORY_SCOPE_AGENT) < target)
        __builtin_amdgcn_s_sleep(1);
}

// ---------------- embedding gather + bf16 convert --------------------------
__global__ __launch_bounds__(256) void embed_kernel(
    const int* __restrict__ x, const float* __restrict__ emb,
    unsigned short* __restrict__ xs)
{
    int e = blockIdx.x * 256 + threadIdx.x;     // 0 .. 2097151
    int t  = e >> 12;
    int r  = e & 4095;
    int b  = r >> 6;
    int k8 = (r & 63) << 3;
    int tok = x[b * 512 + t];                   // x[b][t]
    const float* src = emb + (size_t)tok * 512 + k8;
    unsigned short* dst = xs + ((size_t)(t * 64 + b)) * 512 + k8;
#pragma unroll
    for (int i = 0; i < 8; ++i) dst[i] = f2bf(src[i]);
}

__global__ __launch_bounds__(256) void init_kernel(unsigned int* __restrict__ p, int n)
{
    int i = blockIdx.x * 256 + threadIdx.x;
    if (i < n) p[i] = 0u;
}

#define LDS_GWS_OFF 131072
#define LDS_TOTAL   147456
#define RELIDX      2048
#define RING_MASK   127
#define SLOT_USH    65536   // 64*1024 ushorts per ring slot (131072 B)

// flag layout (dwords in bar[]): L0 WG w -> bar[w*4]; L1 WG w -> bar[512+w*4]
// (16B stride => 4 flags / 64B line; L0 in lines 0..31, L1 in lines 32..63)

// ---------------- persistent LSTM kernel: DATAFLOW version -----------------
__global__ __launch_bounds__(512) void lstm_kernel_df(
    const unsigned short* __restrict__ xs,
    unsigned short* __restrict__ h0ring,  // [128][64][1024] bf16
    unsigned short* __restrict__ h1ring,  // [128][64][1024] bf16
    float* __restrict__ h1f,              // [64][1024] fp32 (final h1)
    unsigned int* __restrict__ bar,
    const float* __restrict__ W0, const float* __restrict__ b0,
    const float* __restrict__ W1, const float* __restrict__ b1)
{
    extern __shared__ char smem[];
    bf16x8* Afrag = (bf16x8*)smem;                    // [nk][2 mtiles][64 lanes]
    float*  gws   = (float*)(smem + LDS_GWS_OFF);     // 8 waves * 512 fp32

    const int wg  = blockIdx.x;
    const int tid = threadIdx.x;
    const bool isL1 = (wg >= 128);
    const int w   = isL1 ? wg - 128 : wg;   // 0..127
    const int w8  = w * 8;
    const int nk  = isL1 ? 64 : 48;
    const float* W = isL1 ? W1 : W0;
    const int wstride = isL1 ? 2048 : 1536;
    const float* bias = isL1 ? b1 : b0;
    unsigned int* myflag = bar + (isL1 ? 512 : 0) + w * 4;

    for (int f = tid; f < nk * 128; f += 512) {
        int kblk = f >> 7;
        int r    = f & 127;
        int mt   = r >> 6;
        int lane = r & 63;
        int m16  = lane & 15;
        int q    = lane >> 4;
        int c    = m16 >> 2;
        int ul   = mt * 4 + (m16 & 3);
        int grow = c * 1024 + w8 + ul;
        const float* src = W + (size_t)grow * wstride + kblk * 32 + q * 8;
        bf16x8 v;
#pragma unroll
        for (int i = 0; i < 8; ++i) v[i] = (short)f2bf(src[i]);
        Afrag[f] = v;
    }

    const int lane = tid & 63;
    const int wid  = tid >> 6;         // 0..7
    const int wv   = wid & 3;          // batch tile
    const int kh   = tid >> 8;         // K-half 0/1
    const int n16  = lane & 15;
    const int q4   = lane >> 4;
    const int brow = wv * 16 + n16;

    float bi[2][4];
#pragma unroll
    for (int cell = 0; cell < 2; ++cell) {
        int j = w8 + q4 * 2 + cell;
#pragma unroll
        for (int c = 0; c < 4; ++c) bi[cell][c] = bias[c * 1024 + j];
    }
    float cst0 = 0.f, cst1 = 0.f;

    __syncthreads();

    f32x4 acc0 = (f32x4){0.f, 0.f, 0.f, 0.f};
    f32x4 acc1 = (f32x4){0.f, 0.f, 0.f, 0.f};

    // pre-loop: L0's xs-part for t=0
    if (!isL1) {
        const unsigned short* xsp = xs + ((size_t)brow) * 512 + q4 * 8;
        int k0 = kh ? 8 : 0;
#pragma unroll
        for (int kb2 = 0; kb2 < 8; ++kb2) {
            int kb = k0 + kb2;
            bf16x8 bf = *(const bf16x8*)(xsp + kb * 32);
            acc0 = mfma16(Afrag[(kb * 2 + 0) * 64 + lane], bf, acc0);
            acc1 = mfma16(Afrag[(kb * 2 + 1) * 64 + lane], bf, acc1);
        }
    }

    for (int tick = 0; tick < 513; ++tick) {
        // ---- dependency wait ----
        if (tick > 0) {
            unsigned target = (unsigned)tick;
            if ((tick & RING_MASK) == 0) {
                // rendezvous: all 256 flags >= tick, then L1+L2 invalidate
                if (wid == 0) {
                    spin_ge(bar +       lane * 4, target);   // L0 flags 0..63
                    spin_ge(bar + 256 + lane * 4, target);   // L0 flags 64..127
                    spin_ge(bar + 512 + lane * 4, target);   // L1 flags 0..63
                    spin_ge(bar + 768 + lane * 4, target);   // L1 flags 64..127
                }
                __syncthreads();
                if (wid == 0)
                    __builtin_amdgcn_fence(__ATOMIC_ACQUIRE, "agent");
                __syncthreads();
            } else {
                if (!isL1) {
                    if (wid == 0)      spin_ge(bar +       lane * 4, target);
                    else if (wid == 4) spin_ge(bar + 256 + lane * 4, target);
                } else {
                    if (wid == 0) {                       // h0(t) producers
                        spin_ge(bar +       lane * 4, target);
                        spin_ge(bar + 256 + lane * 4, target);
                    } else if (wid == 4) {                // h1(t-1) producers
                        spin_ge(bar + 512 + lane * 4, target);
                        spin_ge(bar + 768 + lane * 4, target);
                    }
                }
                __syncthreads();
            }
            asm volatile("" ::: "memory");
        }

        int t = isL1 ? (tick - 1) : tick;
        if (t >= 0 && t < 512) {
            if (!isL1) {
                // h0(t-1): cacheable loads from ring slot (t-1)&127
                if (t > 0) {
                    const unsigned short* hp =
                        h0ring + (size_t)((t - 1) & RING_MASK) * SLOT_USH
                               + (size_t)brow * 1024 + q4 * 8;
                    int k0 = kh ? 32 : 16;
#pragma unroll 8
                    for (int kb2 = 0; kb2 < 16; ++kb2) {
                        int kb = k0 + kb2;
                        bf16x8 bf = *(const bf16x8*)(hp + (kb - 16) * 32);
                        acc0 = mfma16(Afrag[(kb * 2 + 0) * 64 + lane], bf, acc0);
                        acc1 = mfma16(Afrag[(kb * 2 + 1) * 64 + lane], bf, acc1);
                    }
                }
            } else if (kh == 0) {
                // h0(t): ring slot t&127
                const unsigned short* hp0 =
                    h0ring + (size_t)(t & RING_MASK) * SLOT_USH
                           + (size_t)brow * 1024 + q4 * 8;
#pragma unroll 8
                for (int kb = 0; kb < 32; ++kb) {
                    bf16x8 bf = *(const bf16x8*)(hp0 + kb * 32);
                    acc0 = mfma16(Afrag[(kb * 2 + 0) * 64 + lane], bf, acc0);
                    acc1 = mfma16(Afrag[(kb * 2 + 1) * 64 + lane], bf, acc1);
                }
            } else {
                // h1(t-1): ring slot (t-1)&127
                if (t > 0) {
                    const unsigned short* hp1 =
                        h1ring + (size_t)((t - 1) & RING_MASK) * SLOT_USH
                               + (size_t)brow * 1024 + q4 * 8;
#pragma unroll 8
                    for (int kb = 32; kb < 64; ++kb) {
                        bf16x8 bf = *(const bf16x8*)(hp1 + (kb - 32) * 32);
                        acc0 = mfma16(Afrag[(kb * 2 + 0) * 64 + lane], bf, acc0);
                        acc1 = mfma16(Afrag[(kb * 2 + 1) * 64 + lane], bf, acc1);
                    }
                }
            }

            float* g = gws + wid * 512;
#pragma unroll
            for (int r = 0; r < 4; ++r) {
                g[      q4 * 64 + r * 16 + n16] = acc0[r];
                g[256 + q4 * 64 + r * 16 + n16] = acc1[r];
            }
            __syncthreads();   // (A) partials visible

            if (kh == 0) {
                unsigned short* hw =
                    (isL1 ? h1ring : h0ring) + (size_t)(t & RING_MASK) * SLOT_USH;
                unsigned short hbits[2];
                float hflt[2];
#pragma unroll
                for (int cell = 0; cell < 2; ++cell) {
                    int ul = q4 * 2 + cell;
                    int mt = ul >> 2;
                    int r  = ul & 3;
                    const float* g0 = gws + wv * 512 + mt * 256;
                    const float* g1 = gws + (wv + 4) * 512 + mt * 256;
                    float xi = g0[0 * 64 + r * 16 + n16] + g1[0 * 64 + r * 16 + n16] + bi[cell][0];
                    float xf = g0[1 * 64 + r * 16 + n16] + g1[1 * 64 + r * 16 + n16] + bi[cell][1];
                    float xg = g0[2 * 64 + r * 16 + n16] + g1[2 * 64 + r * 16 + n16] + bi[cell][2];
                    float xo = g0[3 * 64 + r * 16 + n16] + g1[3 * 64 + r * 16 + n16] + bi[cell][3];
                    float si = 1.f / (1.f + expf(-xi));
                    float sf = 1.f / (1.f + expf(-xf));
                    float tg = tanhf(xg);
                    float so = 1.f / (1.f + expf(-xo));
                    float cprev = cell ? cst1 : cst0;
                    float cn = sf * cprev + si * tg;
                    if (cell) cst1 = cn; else cst0 = cn;
                    float h = so * tanhf(cn);
                    hflt[cell]  = h;
                    hbits[cell] = f2bf(h);
                }
                unsigned int hv = (unsigned)hbits[0] | ((unsigned)hbits[1] << 16);
                unsigned int* hp32 =
                    (unsigned int*)(hw + (size_t)brow * 1024 + w8 + q4 * 2);
                __hip_atomic_store(hp32, hv, __ATOMIC_RELAXED, __HIP_MEMORY_SCOPE_AGENT);
                if (isL1 && t == 511) {
                    h1f[(size_t)brow * 1024 + w8 + q4 * 2 + 0] = hflt[0];
                    h1f[(size_t)brow * 1024 + w8 + q4 * 2 + 1] = hflt[1];
                }
            }
            __syncthreads();   // (B) per-wave vmcnt(0) drain before s_barrier
        }

        // ---- arrive: publish this WG's completed-tick counter ----
        if (tick < 512) {
            if (tid == 0) {
                asm volatile("s_waitcnt vmcnt(0)" ::: "memory");
                __hip_atomic_store(myflag, (unsigned)(tick + 1),
                                   __ATOMIC_RELAXED, __HIP_MEMORY_SCOPE_AGENT);
            }
            acc0 = (f32x4){0.f, 0.f, 0.f, 0.f};
            acc1 = (f32x4){0.f, 0.f, 0.f, 0.f};
            int tn = tick + 1;
            if (!isL1 && tn < 512) {    // xs-part overlaps flag propagation
                const unsigned short* xsp =
                    xs + ((size_t)(tn * 64 + brow)) * 512 + q4 * 8;
                int k0 = kh ? 8 : 0;
#pragma unroll
                for (int kb2 = 0; kb2 < 8; ++kb2) {
                    int kb = k0 + kb2;
                    bf16x8 bf = *(const bf16x8*)(xsp + kb * 32);
                    acc0 = mfma16(Afrag[(kb * 2 + 0) * 64 + lane], bf, acc0);
                    acc1 = mfma16(Afrag[(kb * 2 + 1) * 64 + lane], bf, acc1);
                }
            }
        }
    }
}

// ---------------- persistent LSTM kernel: round-3 FALLBACK -----------------
__global__ __launch_bounds__(512) void lstm_kernel_fb(
    const unsigned short* __restrict__ xs,
    unsigned short* __restrict__ h0buf,
    unsigned short* __restrict__ h1buf,
    float* __restrict__ h1f,
    unsigned int* __restrict__ bar,
    const float* __restrict__ W0, const float* __restrict__ b0,
    const float* __restrict__ W1, const float* __restrict__ b1)
{
    extern __shared__ char smem[];
    bf16x8* Afrag = (bf16x8*)smem;
    float*  gws   = (float*)(smem + LDS_GWS_OFF);

    const int wg  = blockIdx.x;
    const int tid = threadIdx.x;
    const bool isL1 = (wg >= 128);
    const int w   = isL1 ? wg - 128 : wg;
    const int w8  = w * 8;
    const int nk  = isL1 ? 64 : 48;
    const float* W = isL1 ? W1 : W0;
    const int wstride = isL1 ? 2048 : 1536;
    const float* bias = isL1 ? b1 : b0;

    for (int f = tid; f < nk * 128; f += 512) {
        int kblk = f >> 7;
        int r    = f & 127;
        int mt   = r >> 6;
        int lane = r & 63;
        int m16  = lane & 15;
        int q    = lane >> 4;
        int c    = m16 >> 2;
        int ul   = mt * 4 + (m16 & 3);
        int grow = c * 1024 + w8 + ul;
        const float* src = W + (size_t)grow * wstride + kblk * 32 + q * 8;
        bf16x8 v;
#pragma unroll
        for (int i = 0; i < 8; ++i) v[i] = (short)f2bf(src[i]);
        Afrag[f] = v;
    }

    const int lane = tid & 63;
    const int wid  = tid >> 6;
    const int wv   = wid & 3;
    const int kh   = tid >> 8;
    const int n16  = lane & 15;
    const int q4   = lane >> 4;
    const int brow = wv * 16 + n16;

    float bi[2][4];
#pragma unroll
    for (int cell = 0; cell < 2; ++cell) {
        int j = w8 + q4 * 2 + cell;
#pragma unroll
        for (int c = 0; c < 4; ++c) bi[cell][c] = bias[c * 1024 + j];
    }
    float cst0 = 0.f, cst1 = 0.f;

    __syncthreads();

    f32x4 acc0 = (f32x4){0.f, 0.f, 0.f, 0.f};
    f32x4 acc1 = (f32x4){0.f, 0.f, 0.f, 0.f};

    if (!isL1) {
        const unsigned short* xsp = xs + ((size_t)brow) * 512 + q4 * 8;
        int k0 = kh ? 8 : 0;
#pragma unroll
        for (int kb2 = 0; kb2 < 8; ++kb2) {
            int kb = k0 + kb2;
            bf16x8 bf = *(const bf16x8*)(xsp + kb * 32);
            acc0 = mfma16(Afrag[(kb * 2 + 0) * 64 + lane], bf, acc0);
            acc1 = mfma16(Afrag[(kb * 2 + 1) * 64 + lane], bf, acc1);
        }
    }

    for (int tick = 0; tick < 513; ++tick) {
        if (tick > 0) {
            unsigned target = (unsigned)tick;
            if (wg == 0) {
                if (tid < 256) {
                    while (__hip_atomic_load(&bar[tid * 8], __ATOMIC_RELAXED,
                                             __HIP_MEMORY_SCOPE_AGENT) < target)
                        __builtin_amdgcn_s_sleep(1);
                }
                __syncthreads();
                if (tid < 8)
                    __hip_atomic_store(&bar[RELIDX + tid * 32], target,
                                       __ATOMIC_RELAXED, __HIP_MEMORY_SCOPE_AGENT);
            } else {
                if (tid == 0) {
                    while (__hip_atomic_load(&bar[RELIDX + (wg & 7) * 32],
                                             __ATOMIC_RELAXED,
                                             __HIP_MEMORY_SCOPE_AGENT) < target)
                        __builtin_amdgcn_s_sleep(1);
                }
                __syncthreads();
            }
            asm volatile("" ::: "memory");
        }

        int t = isL1 ? (tick - 1) : tick;
        if (t >= 0 && t < 512) {
            const int p = t & 1;

            if (!isL1) {
                const unsigned short* hp =
                    h0buf + (size_t)(p ^ 1) * 65536 + (size_t)brow * 1024 + q4 * 8;
                int k0 = kh ? 32 : 16;
#pragma unroll 8
                for (int kb2 = 0; kb2 < 16; ++kb2) {
                    int kb = k0 + kb2;
                    bf16x8 bf = ldh(hp + (kb - 16) * 32);
                    acc0 = mfma16(Afrag[(kb * 2 + 0) * 64 + lane], bf, acc0);
                    acc1 = mfma16(Afrag[(kb * 2 + 1) * 64 + lane], bf, acc1);
                }
            } else if (kh == 0) {
                const unsigned short* hp0 =
                    h0buf + (size_t)p * 65536 + (size_t)brow * 1024 + q4 * 8;
#pragma unroll 8
                for (int kb = 0; kb < 32; ++kb) {
                    bf16x8 bf = ldh(hp0 + kb * 32);
                    acc0 = mfma16(Afrag[(kb * 2 + 0) * 64 + lane], bf, acc0);
                    acc1 = mfma16(Afrag[(kb * 2 + 1) * 64 + lane], bf, acc1);
                }
            } else {
                const unsigned short* hp1 =
                    h1buf + (size_t)(p ^ 1) * 65536 + (size_t)brow * 1024 + q4 * 8;
#pragma unroll 8
                for (int kb = 32; kb < 64; ++kb) {
                    bf16x8 bf = ldh(hp1 + (kb - 32) * 32);
                    acc0 = mfma16(Afrag[(kb * 2 + 0) * 64 + lane], bf, acc0);
                    acc1 = mfma16(Afrag[(kb * 2 + 1) * 64 + lane], bf, acc1);
                }
            }

            float* g = gws + wid * 512;
#pragma unroll
            for (int r = 0; r < 4; ++r) {
                g[      q4 * 64 + r * 16 + n16] = acc0[r];
                g[256 + q4 * 64 + r * 16 + n16] = acc1[r];
            }
            __syncthreads();

            if (kh == 0) {
                unsigned short* hw = (isL1 ? h1buf : h0buf) + (size_t)p * 65536;
                unsigned short hbits[2];
                float hflt[2];
#pragma unroll
                for (int cell = 0; cell < 2; ++cell) {
                    int ul = q4 * 2 + cell;
                    int mt = ul >> 2;
                    int r  = ul & 3;
                    const float* g0 = gws + wv * 512 + mt * 256;
                    const float* g1 = gws + (wv + 4) * 512 + mt * 256;
                    float xi = g0[0 * 64 + r * 16 + n16] + g1[0 * 64 + r * 16 + n16] + bi[cell][0];
                    float xf = g0[1 * 64 + r * 16 + n16] + g1[1 * 64 + r * 16 + n16] + bi[cell][1];
                    float xg = g0[2 * 64 + r * 16 + n16] + g1[2 * 64 + r * 16 + n16] + bi[cell][2];
                    float xo = g0[3 * 64 + r * 16 + n16] + g1[3 * 64 + r * 16 + n16] + bi[cell][3];
                    float si = 1.f / (1.f + expf(-xi));
                    float sf = 1.f / (1.f + expf(-xf));
                    float tg = tanhf(xg);
                    float so = 1.f / (1.f + expf(-xo));
                    float cprev = cell ? cst1 : cst0;
                    float cn = sf * cprev + si * tg;
                    if (cell) cst1 = cn; else cst0 = cn;
                    float h = so * tanhf(cn);
                    hflt[cell]  = h;
                    hbits[cell] = f2bf(h);
                }
                unsigned int hv = (unsigned)hbits[0] | ((unsigned)hbits[1] << 16);
                unsigned int* hp32 =
                    (unsigned int*)(hw + (size_t)brow * 1024 + w8 + q4 * 2);
                __hip_atomic_store(hp32, hv, __ATOMIC_RELAXED, __HIP_MEMORY_SCOPE_AGENT);
                if (isL1 && t == 511) {
                    h1f[(size_t)brow * 1024 + w8 + q4 * 2 + 0] = hflt[0];
                    h1f[(size_t)brow * 1024 + w8 + q4 * 2 + 1] = hflt[1];
                }
            }
            __syncthreads();
        }

        if (tick < 512) {
            if (tid == 0) {
                asm volatile("s_waitcnt vmcnt(0)" ::: "memory");
                __hip_atomic_store(&bar[wg * 8], (unsigned)(tick + 1),
                                   __ATOMIC_RELAXED, __HIP_MEMORY_SCOPE_AGENT);
            }
            acc0 = (f32x4){0.f, 0.f, 0.f, 0.f};
            acc1 = (f32x4){0.f, 0.f, 0.f, 0.f};
            int tn = tick + 1;
            if (!isL1 && tn < 512) {
                const unsigned short* xsp =
                    xs + ((size_t)(tn * 64 + brow)) * 512 + q4 * 8;
                int k0 = kh ? 8 : 0;
#pragma unroll
                for (int kb2 = 0; kb2 < 8; ++kb2) {
                    int kb = k0 + kb2;
                    bf16x8 bf = *(const bf16x8*)(xsp + kb * 32);
                    acc0 = mfma16(Afrag[(kb * 2 + 0) * 64 + lane], bf, acc0);
                    acc1 = mfma16(Afrag[(kb * 2 + 1) * 64 + lane], bf, acc1);
                }
            }
        }
    }
}

// ---------------- classifier: out = h1f @ V.T + bV -------------------------
__global__ __launch_bounds__(64) void cls_kernel(
    const float* __restrict__ h1f, const float* __restrict__ V,
    const float* __restrict__ bV, float* __restrict__ out)
{
    int b = blockIdx.x;
    int lane = threadIdx.x;
    float p[10];
#pragma unroll
    for (int c = 0; c < 10; ++c) p[c] = 0.f;
    for (int k = lane; k < 1024; k += 64) {
        float h = h1f[(size_t)b * 1024 + k];
#pragma unroll
        for (int c = 0; c < 10; ++c) p[c] += h * V[(size_t)c * 1024 + k];
    }
#pragma unroll
    for (int c = 0; c < 10; ++c) {
        float v = p[c];
#pragma unroll
        for (int off = 32; off > 0; off >>= 1) v += __shfl_down(v, off);
        if (lane == 0) out[b * 10 + c] = v + bV[c];
    }
}

// ---------------- launch ---------------------------------------------------
// RING ws layout (bytes), total 67,387,392:
//   [0, 33554432)            xs  bf16 [512][64][512]
//   +33554432  h0ring bf16 [128][64][1024]   (16777216)
//   +50331648  h1ring bf16 [128][64][1024]   (16777216)
//   +67108864  h1f    fp32 [64][1024]        (262144)
//   +67371008  flags (16384)
// FALLBACK layout: as round 3 (34.3 MB).
extern "C" void kernel_launch(void* const* d_in, const int* in_sizes, int n_in,
                              void* d_out, int out_size, void* d_ws, size_t ws_size,
                              hipStream_t stream)
{
    const int*   x   = (const int*)d_in[0];
    const float* emb = (const float*)d_in[1];
    const float* W0  = (const float*)d_in[2];
    const float* b0  = (const float*)d_in[3];
    const float* W1  = (const float*)d_in[4];
    const float* b1  = (const float*)d_in[5];
    const float* V   = (const float*)d_in[6];
    const float* bV  = (const float*)d_in[7];
    float* out = (float*)d_out;

    char* ws = (char*)d_ws;
    unsigned short* xs = (unsigned short*)ws;

    if (ws_size >= 67387392ULL) {
        unsigned short* h0r = (unsigned short*)(ws + 33554432);
        unsigned short* h1r = (unsigned short*)(ws + 50331648);
        float*          h1f = (float*)(ws + 67108864);
        unsigned int*   bar = (unsigned int*)(ws + 67371008);

        hipLaunchKernelGGL(init_kernel, dim3(16), dim3(256), 0, stream,
                           bar, 4096);
        hipLaunchKernelGGL(embed_kernel, dim3(8192), dim3(256), 0, stream, x, emb, xs);
        hipLaunchKernelGGL(lstm_kernel_df, dim3(256), dim3(512), LDS_TOTAL, stream,
                           xs, h0r, h1r, h1f, bar, W0, b0, W1, b1);
        hipLaunchKernelGGL(cls_kernel, dim3(64), dim3(64), 0, stream, h1f, V, bV, out);
    } else {
        char* dyn = ws + 33554432;
        unsigned short* h0  = (unsigned short*)(dyn);
        unsigned short* h1  = (unsigned short*)(dyn + 262144);
        float*          h1f = (float*)(dyn + 524288);
        unsigned int*   bar = (unsigned int*)(dyn + 786432);

        hipLaunchKernelGGL(init_kernel, dim3(780), dim3(256), 0, stream,
                           (unsigned int*)dyn, 199680);
        hipLaunchKernelGGL(embed_kernel, dim3(8192), dim3(256), 0, stream, x, emb, xs);
        hipLaunchKernelGGL(lstm_kernel_fb, dim3(256), dim3(512), LDS_TOTAL, stream,
                           xs, h0, h1, h1f, bar, W0, b0, W1, b1);
        hipLaunchKernelGGL(cls_kernel, dim3(64), dim3(64), 0, stream, h1f, V, bV, out);
    }
}

// Round 6
// 4857.737 us; speedup vs baseline: 1.1223x; 1.1223x over previous
//
#include <hip/hip_runtime.h>
#include <stdint.h>

// ---------------------------------------------------------------------------
// 2-layer LSTM, B=64, T=512, E=512, H=1024, then [64,1024]@V.T+bV -> [64,10].
//
// Round 6: attack same-line polling contention (R4~R5 showed hop count is
// NOT the spine; ~256 pollers serializing on each flag/release line is).
//  - producer tick-flags replicated to 16 banks (one 16-lane store inst);
//    consumer WG w polls only bank w&15 -> <=16 pollers per line.
//  - direct gather, no central WG: wave0 polls 128 L0 flags in 2 wave-wide
//    sc1 loads + __all; L1's wave4 polls L1 flags concurrently; s_sleep(2)
//    backoff between poll rounds.
//  - ring + revolution rendezvous/acquire-fence kept (bank-local poll-all).
//  - fast epilogue: __expf + v_rcp based sigmoid/tanh (clamped).
// ---------------------------------------------------------------------------

typedef __attribute__((ext_vector_type(8))) short bf16x8;   // 8 bf16 in 4 VGPRs
typedef __attribute__((ext_vector_type(4))) float f32x4;

__device__ __forceinline__ unsigned short f2bf(float x) {
    unsigned u = __float_as_uint(x);
    u = (u + 0x7FFFu + ((u >> 16) & 1u)) >> 16;   // RNE
    return (unsigned short)u;
}

__device__ __forceinline__ f32x4 mfma16(bf16x8 a, bf16x8 b, f32x4 c) {
    return __builtin_amdgcn_mfma_f32_16x16x32_bf16(a, b, c, 0, 0, 0);
}

// agent-scope (IC-direct) 16B load — fallback path only
__device__ __forceinline__ bf16x8 ldh(const unsigned short* p) {
    union { unsigned long long q[2]; bf16x8 v; } u;
    unsigned long long* a = (unsigned long long*)p;
    u.q[0] = __hip_atomic_load(a + 0, __ATOMIC_RELAXED, __HIP_MEMORY_SCOPE_AGENT);
    u.q[1] = __hip_atomic_load(a + 1, __ATOMIC_RELAXED, __HIP_MEMORY_SCOPE_AGENT);
    return u.v;
}

// poll 128 flags (2 wave-wide sc1 loads) until all >= target
__device__ __forceinline__ void poll128(const unsigned int* base, int lane,
                                        unsigned target) {
    const unsigned int* p0 = base + lane;
    const unsigned int* p1 = base + 64 + lane;
    for (;;) {
        unsigned a = __hip_atomic_load(p0, __ATOMIC_RELAXED, __HIP_MEMORY_SCOPE_AGENT);
        unsigned b = __hip_atomic_load(p1, __ATOMIC_RELAXED, __HIP_MEMORY_SCOPE_AGENT);
        if (__all((int)((a >= target) && (b >= target)))) break;
        __builtin_amdgcn_s_sleep(2);
    }
}

__device__ __forceinline__ float fsigm(float x) {
    x = fminf(fmaxf(x, -60.f), 60.f);
    return __builtin_amdgcn_rcpf(1.f + __expf(-x));
}
__device__ __forceinline__ float ftanh(float x) {
    x = fminf(fmaxf(x, -15.f), 15.f);
    float e = __expf(-2.f * x);
    return (1.f - e) * __builtin_amdgcn_rcpf(1.f + e);
}

// ---------------- embedding gather + bf16 convert --------------------------
__global__ __launch_bounds__(256) void embed_kernel(
    const int* __restrict__ x, const float* __restrict__ emb,
    unsigned short* __restrict__ xs)
{
    int e = blockIdx.x * 256 + threadIdx.x;     // 0 .. 2097151
    int t  = e >> 12;
    int r  = e & 4095;
    int b  = r >> 6;
    int k8 = (r & 63) << 3;
    int tok = x[b * 512 + t];                   // x[b][t]
    const float* src = emb + (size_t)tok * 512 + k8;
    unsigned short* dst = xs + ((size_t)(t * 64 + b)) * 512 + k8;
#pragma unroll
    for (int i = 0; i < 8; ++i) dst[i] = f2bf(src[i]);
}

__global__ __launch_bounds__(256) void init_kernel(unsigned int* __restrict__ p, int n)
{
    int i = blockIdx.x * 256 + threadIdx.x;
    if (i < n) p[i] = 0u;
}

#define LDS_GWS_OFF 131072
#define LDS_TOTAL   147456
#define RELIDX      2048
#define RING_MASK   127
#define SLOT_USH    65536   // 64*1024 ushorts per ring slot (131072 B)
#define NBANK       16
// flags: bar[bank*256 + layer*128 + w], bank<16. 16 KB total.

// ---------------- persistent LSTM kernel: DATAFLOW + banked flags ----------
__global__ __launch_bounds__(512) void lstm_kernel_df(
    const unsigned short* __restrict__ xs,
    unsigned short* __restrict__ h0ring,  // [128][64][1024] bf16
    unsigned short* __restrict__ h1ring,  // [128][64][1024] bf16
    float* __restrict__ h1f,              // [64][1024] fp32 (final h1)
    unsigned int* __restrict__ bar,
    const float* __restrict__ W0, const float* __restrict__ b0,
    const float* __restrict__ W1, const float* __restrict__ b1)
{
    extern __shared__ char smem[];
    bf16x8* Afrag = (bf16x8*)smem;                    // [nk][2 mtiles][64 lanes]
    float*  gws   = (float*)(smem + LDS_GWS_OFF);     // 8 waves * 512 fp32

    const int wg  = blockIdx.x;
    const int tid = threadIdx.x;
    const bool isL1 = (wg >= 128);
    const int w   = isL1 ? wg - 128 : wg;   // 0..127
    const int w8  = w * 8;
    const int nk  = isL1 ? 64 : 48;
    const float* W = isL1 ? W1 : W0;
    const int wstride = isL1 ? 2048 : 1536;
    const float* bias = isL1 ? b1 : b0;
    const unsigned int* bk = bar + (wg & (NBANK - 1)) * 256;   // my poll bank

    for (int f = tid; f < nk * 128; f += 512) {
        int kblk = f >> 7;
        int r    = f & 127;
        int mt   = r >> 6;
        int lane = r & 63;
        int m16  = lane & 15;
        int q    = lane >> 4;
        int c    = m16 >> 2;
        int ul   = mt * 4 + (m16 & 3);
        int grow = c * 1024 + w8 + ul;
        const float* src = W + (size_t)grow * wstride + kblk * 32 + q * 8;
        bf16x8 v;
#pragma unroll
        for (int i = 0; i < 8; ++i) v[i] = (short)f2bf(src[i]);
        Afrag[f] = v;
    }

    const int lane = tid & 63;
    const int wid  = tid >> 6;         // 0..7
    const int wv   = wid & 3;          // batch tile
    const int kh   = tid >> 8;         // K-half 0/1
    const int n16  = lane & 15;
    const int q4   = lane >> 4;
    const int brow = wv * 16 + n16;

    float bi[2][4];
#pragma unroll
    for (int cell = 0; cell < 2; ++cell) {
        int j = w8 + q4 * 2 + cell;
#pragma unroll
        for (int c = 0; c < 4; ++c) bi[cell][c] = bias[c * 1024 + j];
    }
    float cst0 = 0.f, cst1 = 0.f;

    __syncthreads();

    f32x4 acc0 = (f32x4){0.f, 0.f, 0.f, 0.f};
    f32x4 acc1 = (f32x4){0.f, 0.f, 0.f, 0.f};

    // pre-loop: L0's xs-part for t=0
    if (!isL1) {
        const unsigned short* xsp = xs + ((size_t)brow) * 512 + q4 * 8;
        int k0 = kh ? 8 : 0;
#pragma unroll
        for (int kb2 = 0; kb2 < 8; ++kb2) {
            int kb = k0 + kb2;
            bf16x8 bf = *(const bf16x8*)(xsp + kb * 32);
            acc0 = mfma16(Afrag[(kb * 2 + 0) * 64 + lane], bf, acc0);
            acc1 = mfma16(Afrag[(kb * 2 + 1) * 64 + lane], bf, acc1);
        }
    }

    for (int tick = 0; tick < 513; ++tick) {
        // ---- dependency wait (banked flags, <=16 pollers/line) ----
        if (tick > 0) {
            unsigned target = (unsigned)tick;
            if ((tick & RING_MASK) == 0) {
                // rendezvous: all 256 flags >= tick, then L1+L2 invalidate
                if (wid == 0) {
                    poll128(bk,       lane, target);   // L0 flags
                    poll128(bk + 128, lane, target);   // L1 flags
                }
                __syncthreads();
                if (wid == 0)
                    __builtin_amdgcn_fence(__ATOMIC_ACQUIRE, "agent");
                __syncthreads();
            } else {
                if (!isL1) {
                    if (wid == 0) poll128(bk, lane, target);        // L0 flags
                } else {
                    if (wid == 0)      poll128(bk,       lane, target);  // h0 prod
                    else if (wid == 4) poll128(bk + 128, lane, target);  // h1 prod
                }
                __syncthreads();
            }
        }

        int t = isL1 ? (tick - 1) : tick;
        if (t >= 0 && t < 512) {
            if (!isL1) {
                // h0(t-1): cacheable loads from ring slot (t-1)&127
                if (t > 0) {
                    const unsigned short* hp =
                        h0ring + (size_t)((t - 1) & RING_MASK) * SLOT_USH
                               + (size_t)brow * 1024 + q4 * 8;
                    int k0 = kh ? 32 : 16;
#pragma unroll 8
                    for (int kb2 = 0; kb2 < 16; ++kb2) {
                        int kb = k0 + kb2;
                        bf16x8 bf = *(const bf16x8*)(hp + (kb - 16) * 32);
                        acc0 = mfma16(Afrag[(kb * 2 + 0) * 64 + lane], bf, acc0);
                        acc1 = mfma16(Afrag[(kb * 2 + 1) * 64 + lane], bf, acc1);
                    }
                }
            } else if (kh == 0) {
                // h0(t): ring slot t&127
                const unsigned short* hp0 =
                    h0ring + (size_t)(t & RING_MASK) * SLOT_USH
                           + (size_t)brow * 1024 + q4 * 8;
#pragma unroll 8
                for (int kb = 0; kb < 32; ++kb) {
                    bf16x8 bf = *(const bf16x8*)(hp0 + kb * 32);
                    acc0 = mfma16(Afrag[(kb * 2 + 0) * 64 + lane], bf, acc0);
                    acc1 = mfma16(Afrag[(kb * 2 + 1) * 64 + lane], bf, acc1);
                }
            } else {
                // h1(t-1): ring slot (t-1)&127
                if (t > 0) {
                    const unsigned short* hp1 =
                        h1ring + (size_t)((t - 1) & RING_MASK) * SLOT_USH
                               + (size_t)brow * 1024 + q4 * 8;
#pragma unroll 8
                    for (int kb = 32; kb < 64; ++kb) {
                        bf16x8 bf = *(const bf16x8*)(hp1 + (kb - 32) * 32);
                        acc0 = mfma16(Afrag[(kb * 2 + 0) * 64 + lane], bf, acc0);
                        acc1 = mfma16(Afrag[(kb * 2 + 1) * 64 + lane], bf, acc1);
                    }
                }
            }

            float* g = gws + wid * 512;
#pragma unroll
            for (int r = 0; r < 4; ++r) {
                g[      q4 * 64 + r * 16 + n16] = acc0[r];
                g[256 + q4 * 64 + r * 16 + n16] = acc1[r];
            }
            __syncthreads();   // (A) partials visible

            if (kh == 0) {
                unsigned short* hw =
                    (isL1 ? h1ring : h0ring) + (size_t)(t & RING_MASK) * SLOT_USH;
                unsigned short hbits[2];
                float hflt[2];
#pragma unroll
                for (int cell = 0; cell < 2; ++cell) {
                    int ul = q4 * 2 + cell;
                    int mt = ul >> 2;
                    int r  = ul & 3;
                    const float* g0 = gws + wv * 512 + mt * 256;
                    const float* g1 = gws + (wv + 4) * 512 + mt * 256;
                    float xi = g0[0 * 64 + r * 16 + n16] + g1[0 * 64 + r * 16 + n16] + bi[cell][0];
                    float xf = g0[1 * 64 + r * 16 + n16] + g1[1 * 64 + r * 16 + n16] + bi[cell][1];
                    float xg = g0[2 * 64 + r * 16 + n16] + g1[2 * 64 + r * 16 + n16] + bi[cell][2];
                    float xo = g0[3 * 64 + r * 16 + n16] + g1[3 * 64 + r * 16 + n16] + bi[cell][3];
                    float si = fsigm(xi);
                    float sf = fsigm(xf);
                    float tg = ftanh(xg);
                    float so = fsigm(xo);
                    float cprev = cell ? cst1 : cst0;
                    float cn = sf * cprev + si * tg;
                    if (cell) cst1 = cn; else cst0 = cn;
                    float h = so * ftanh(cn);
                    hflt[cell]  = h;
                    hbits[cell] = f2bf(h);
                }
                unsigned int hv = (unsigned)hbits[0] | ((unsigned)hbits[1] << 16);
                unsigned int* hp32 =
                    (unsigned int*)(hw + (size_t)brow * 1024 + w8 + q4 * 2);
                __hip_atomic_store(hp32, hv, __ATOMIC_RELAXED, __HIP_MEMORY_SCOPE_AGENT);
                if (isL1 && t == 511) {
                    h1f[(size_t)brow * 1024 + w8 + q4 * 2 + 0] = hflt[0];
                    h1f[(size_t)brow * 1024 + w8 + q4 * 2 + 1] = hflt[1];
                }
            }
            __syncthreads();   // (B) per-wave vmcnt(0) drain before s_barrier
        }

        // ---- arrive: publish tick counter to all 16 banks (1 store inst) --
        if (tick < 512) {
            if (tid < NBANK) {
                __hip_atomic_store(bar + tid * 256 + (isL1 ? 128 : 0) + w,
                                   (unsigned)(tick + 1),
                                   __ATOMIC_RELAXED, __HIP_MEMORY_SCOPE_AGENT);
            }
            acc0 = (f32x4){0.f, 0.f, 0.f, 0.f};
            acc1 = (f32x4){0.f, 0.f, 0.f, 0.f};
            int tn = tick + 1;
            if (!isL1 && tn < 512) {    // xs-part overlaps flag propagation
                const unsigned short* xsp =
                    xs + ((size_t)(tn * 64 + brow)) * 512 + q4 * 8;
                int k0 = kh ? 8 : 0;
#pragma unroll
                for (int kb2 = 0; kb2 < 8; ++kb2) {
                    int kb = k0 + kb2;
                    bf16x8 bf = *(const bf16x8*)(xsp + kb * 32);
                    acc0 = mfma16(Afrag[(kb * 2 + 0) * 64 + lane], bf, acc0);
                    acc1 = mfma16(Afrag[(kb * 2 + 1) * 64 + lane], bf, acc1);
                }
            }
        }
    }
}

// ---------------- persistent LSTM kernel: round-3 FALLBACK -----------------
__global__ __launch_bounds__(512) void lstm_kernel_fb(
    const unsigned short* __restrict__ xs,
    unsigned short* __restrict__ h0buf,
    unsigned short* __restrict__ h1buf,
    float* __restrict__ h1f,
    unsigned int* __restrict__ bar,
    const float* __restrict__ W0, const float* __restrict__ b0,
    const float* __restrict__ W1, const float* __restrict__ b1)
{
    extern __shared__ char smem[];
    bf16x8* Afrag = (bf16x8*)smem;
    float*  gws   = (float*)(smem + LDS_GWS_OFF);

    const int wg  = blockIdx.x;
    const int tid = threadIdx.x;
    const bool isL1 = (wg >= 128);
    const int w   = isL1 ? wg - 128 : wg;
    const int w8  = w * 8;
    const int nk  = isL1 ? 64 : 48;
    const float* W = isL1 ? W1 : W0;
    const int wstride = isL1 ? 2048 : 1536;
    const float* bias = isL1 ? b1 : b0;

    for (int f = tid; f < nk * 128; f += 512) {
        int kblk = f >> 7;
        int r    = f & 127;
        int mt   = r >> 6;
        int lane = r & 63;
        int m16  = lane & 15;
        int q    = lane >> 4;
        int c    = m16 >> 2;
        int ul   = mt * 4 + (m16 & 3);
        int grow = c * 1024 + w8 + ul;
        const float* src = W + (size_t)grow * wstride + kblk * 32 + q * 8;
        bf16x8 v;
#pragma unroll
        for (int i = 0; i < 8; ++i) v[i] = (short)f2bf(src[i]);
        Afrag[f] = v;
    }

    const int lane = tid & 63;
    const int wid  = tid >> 6;
    const int wv   = wid & 3;
    const int kh   = tid >> 8;
    const int n16  = lane & 15;
    const int q4   = lane >> 4;
    const int brow = wv * 16 + n16;

    float bi[2][4];
#pragma unroll
    for (int cell = 0; cell < 2; ++cell) {
        int j = w8 + q4 * 2 + cell;
#pragma unroll
        for (int c = 0; c < 4; ++c) bi[cell][c] = bias[c * 1024 + j];
    }
    float cst0 = 0.f, cst1 = 0.f;

    __syncthreads();

    f32x4 acc0 = (f32x4){0.f, 0.f, 0.f, 0.f};
    f32x4 acc1 = (f32x4){0.f, 0.f, 0.f, 0.f};

    if (!isL1) {
        const unsigned short* xsp = xs + ((size_t)brow) * 512 + q4 * 8;
        int k0 = kh ? 8 : 0;
#pragma unroll
        for (int kb2 = 0; kb2 < 8; ++kb2) {
            int kb = k0 + kb2;
            bf16x8 bf = *(const bf16x8*)(xsp + kb * 32);
            acc0 = mfma16(Afrag[(kb * 2 + 0) * 64 + lane], bf, acc0);
            acc1 = mfma16(Afrag[(kb * 2 + 1) * 64 + lane], bf, acc1);
        }
    }

    for (int tick = 0; tick < 513; ++tick) {
        if (tick > 0) {
            unsigned target = (unsigned)tick;
            if (wg == 0) {
                if (tid < 256) {
                    while (__hip_atomic_load(&bar[tid * 8], __ATOMIC_RELAXED,
                                             __HIP_MEMORY_SCOPE_AGENT) < target)
                        __builtin_amdgcn_s_sleep(1);
                }
                __syncthreads();
                if (tid < 8)
                    __hip_atomic_store(&bar[RELIDX + tid * 32], target,
                                       __ATOMIC_RELAXED, __HIP_MEMORY_SCOPE_AGENT);
            } else {
                if (tid == 0) {
                    while (__hip_atomic_load(&bar[RELIDX + (wg & 7) * 32],
                                             __ATOMIC_RELAXED,
                                             __HIP_MEMORY_SCOPE_AGENT) < target)
                        __builtin_amdgcn_s_sleep(1);
                }
                __syncthreads();
            }
            asm volatile("" ::: "memory");
        }

        int t = isL1 ? (tick - 1) : tick;
        if (t >= 0 && t < 512) {
            const int p = t & 1;

            if (!isL1) {
                const unsigned short* hp =
                    h0buf + (size_t)(p ^ 1) * 65536 + (size_t)brow * 1024 + q4 * 8;
                int k0 = kh ? 32 : 16;
#pragma unroll 8
                for (int kb2 = 0; kb2 < 16; ++kb2) {
                    int kb = k0 + kb2;
                    bf16x8 bf = ldh(hp + (kb - 16) * 32);
                    acc0 = mfma16(Afrag[(kb * 2 + 0) * 64 + lane], bf, acc0);
                    acc1 = mfma16(Afrag[(kb * 2 + 1) * 64 + lane], bf, acc1);
                }
            } else if (kh == 0) {
                const unsigned short* hp0 =
                    h0buf + (size_t)p * 65536 + (size_t)brow * 1024 + q4 * 8;
#pragma unroll 8
                for (int kb = 0; kb < 32; ++kb) {
                    bf16x8 bf = ldh(hp0 + kb * 32);
                    acc0 = mfma16(Afrag[(kb * 2 + 0) * 64 + lane], bf, acc0);
                    acc1 = mfma16(Afrag[(kb * 2 + 1) * 64 + lane], bf, acc1);
                }
            } else {
                const unsigned short* hp1 =
                    h1buf + (size_t)(p ^ 1) * 65536 + (size_t)brow * 1024 + q4 * 8;
#pragma unroll 8
                for (int kb = 32; kb < 64; ++kb) {
                    bf16x8 bf = ldh(hp1 + (kb - 32) * 32);
                    acc0 = mfma16(Afrag[(kb * 2 + 0) * 64 + lane], bf, acc0);
                    acc1 = mfma16(Afrag[(kb * 2 + 1) * 64 + lane], bf, acc1);
                }
            }

            float* g = gws + wid * 512;
#pragma unroll
            for (int r = 0; r < 4; ++r) {
                g[      q4 * 64 + r * 16 + n16] = acc0[r];
                g[256 + q4 * 64 + r * 16 + n16] = acc1[r];
            }
            __syncthreads();

            if (kh == 0) {
                unsigned short* hw = (isL1 ? h1buf : h0buf) + (size_t)p * 65536;
                unsigned short hbits[2];
                float hflt[2];
#pragma unroll
                for (int cell = 0; cell < 2; ++cell) {
                    int ul = q4 * 2 + cell;
                    int mt = ul >> 2;
                    int r  = ul & 3;
                    const float* g0 = gws + wv * 512 + mt * 256;
                    const float* g1 = gws + (wv + 4) * 512 + mt * 256;
                    float xi = g0[0 * 64 + r * 16 + n16] + g1[0 * 64 + r * 16 + n16] + bi[cell][0];
                    float xf = g0[1 * 64 + r * 16 + n16] + g1[1 * 64 + r * 16 + n16] + bi[cell][1];
                    float xg = g0[2 * 64 + r * 16 + n16] + g1[2 * 64 + r * 16 + n16] + bi[cell][2];
                    float xo = g0[3 * 64 + r * 16 + n16] + g1[3 * 64 + r * 16 + n16] + bi[cell][3];
                    float si = fsigm(xi);
                    float sf = fsigm(xf);
                    float tg = ftanh(xg);
                    float so = fsigm(xo);
                    float cprev = cell ? cst1 : cst0;
                    float cn = sf * cprev + si * tg;
                    if (cell) cst1 = cn; else cst0 = cn;
                    float h = so * ftanh(cn);
                    hflt[cell]  = h;
                    hbits[cell] = f2bf(h);
                }
                unsigned int hv = (unsigned)hbits[0] | ((unsigned)hbits[1] << 16);
                unsigned int* hp32 =
                    (unsigned int*)(hw + (size_t)brow * 1024 + w8 + q4 * 2);
                __hip_atomic_store(hp32, hv, __ATOMIC_RELAXED, __HIP_MEMORY_SCOPE_AGENT);
                if (isL1 && t == 511) {
                    h1f[(size_t)brow * 1024 + w8 + q4 * 2 + 0] = hflt[0];
                    h1f[(size_t)brow * 1024 + w8 + q4 * 2 + 1] = hflt[1];
                }
            }
            __syncthreads();
        }

        if (tick < 512) {
            if (tid == 0) {
                asm volatile("s_waitcnt vmcnt(0)" ::: "memory");
                __hip_atomic_store(&bar[wg * 8], (unsigned)(tick + 1),
                                   __ATOMIC_RELAXED, __HIP_MEMORY_SCOPE_AGENT);
            }
            acc0 = (f32x4){0.f, 0.f, 0.f, 0.f};
            acc1 = (f32x4){0.f, 0.f, 0.f, 0.f};
            int tn = tick + 1;
            if (!isL1 && tn < 512) {
                const unsigned short* xsp =
                    xs + ((size_t)(tn * 64 + brow)) * 512 + q4 * 8;
                int k0 = kh ? 8 : 0;
#pragma unroll
                for (int kb2 = 0; kb2 < 8; ++kb2) {
                    int kb = k0 + kb2;
                    bf16x8 bf = *(const bf16x8*)(xsp + kb * 32);
                    acc0 = mfma16(Afrag[(kb * 2 + 0) * 64 + lane], bf, acc0);
                    acc1 = mfma16(Afrag[(kb * 2 + 1) * 64 + lane], bf, acc1);
                }
            }
        }
    }
}

// ---------------- classifier: out = h1f @ V.T + bV -------------------------
__global__ __launch_bounds__(64) void cls_kernel(
    const float* __restrict__ h1f, const float* __restrict__ V,
    const float* __restrict__ bV, float* __restrict__ out)
{
    int b = blockIdx.x;
    int lane = threadIdx.x;
    float p[10];
#pragma unroll
    for (int c = 0; c < 10; ++c) p[c] = 0.f;
    for (int k = lane; k < 1024; k += 64) {
        float h = h1f[(size_t)b * 1024 + k];
#pragma unroll
        for (int c = 0; c < 10; ++c) p[c] += h * V[(size_t)c * 1024 + k];
    }
#pragma unroll
    for (int c = 0; c < 10; ++c) {
        float v = p[c];
#pragma unroll
        for (int off = 32; off > 0; off >>= 1) v += __shfl_down(v, off);
        if (lane == 0) out[b * 10 + c] = v + bV[c];
    }
}

// ---------------- launch ---------------------------------------------------
// RING ws layout (bytes), total 67,387,392:
//   [0, 33554432)            xs  bf16 [512][64][512]
//   +33554432  h0ring bf16 [128][64][1024]   (16777216)
//   +50331648  h1ring bf16 [128][64][1024]   (16777216)
//   +67108864  h1f    fp32 [64][1024]        (262144)
//   +67371008  flags  [16 banks][256] u32    (16384)
// FALLBACK layout: as round 3 (34.3 MB).
extern "C" void kernel_launch(void* const* d_in, const int* in_sizes, int n_in,
                              void* d_out, int out_size, void* d_ws, size_t ws_size,
                              hipStream_t stream)
{
    const int*   x   = (const int*)d_in[0];
    const float* emb = (const float*)d_in[1];
    const float* W0  = (const float*)d_in[2];
    const float* b0  = (const float*)d_in[3];
    const float* W1  = (const float*)d_in[4];
    const float* b1  = (const float*)d_in[5];
    const float* V   = (const float*)d_in[6];
    const float* bV  = (const float*)d_in[7];
    float* out = (float*)d_out;

    char* ws = (char*)d_ws;
    unsigned short* xs = (unsigned short*)ws;

    if (ws_size >= 67387392ULL) {
        unsigned short* h0r = (unsigned short*)(ws + 33554432);
        unsigned short* h1r = (unsigned short*)(ws + 50331648);
        float*          h1f = (float*)(ws + 67108864);
        unsigned int*   bar = (unsigned int*)(ws + 67371008);

        hipLaunchKernelGGL(init_kernel, dim3(16), dim3(256), 0, stream,
                           bar, 4096);
        hipLaunchKernelGGL(embed_kernel, dim3(8192), dim3(256), 0, stream, x, emb, xs);
        hipLaunchKernelGGL(lstm_kernel_df, dim3(256), dim3(512), LDS_TOTAL, stream,
                           xs, h0r, h1r, h1f, bar, W0, b0, W1, b1);
        hipLaunchKernelGGL(cls_kernel, dim3(64), dim3(64), 0, stream, h1f, V, bV, out);
    } else {
        char* dyn = ws + 33554432;
        unsigned short* h0  = (unsigned short*)(dyn);
        unsigned short* h1  = (unsigned short*)(dyn + 262144);
        float*          h1f = (float*)(dyn + 524288);
        unsigned int*   bar = (unsigned int*)(dyn + 786432);

        hipLaunchKernelGGL(init_kernel, dim3(780), dim3(256), 0, stream,
                           (unsigned int*)dyn, 199680);
        hipLaunchKernelGGL(embed_kernel, dim3(8192), dim3(256), 0, stream, x, emb, xs);
        hipLaunchKernelGGL(lstm_kernel_fb, dim3(256), dim3(512), LDS_TOTAL, stream,
                           xs, h0, h1, h1f, bar, W0, b0, W1, b1);
        hipLaunchKernelGGL(cls_kernel, dim3(64), dim3(64), 0, stream, h1f, V, bV, out);
    }
}